// Round 1
// baseline (1441.646 us; speedup 1.0000x reference)
//
#include <hip/hip_runtime.h>
#include <cstdint>
#include <cstddef>

// ---------------------------------------------------------------------------
// BatchedMergedLinear: out = x @ W^T + bias, plus LoRA low-rank correction on
// output column blocks [0,1024) (g=0) and [2048,3072) (g=1):
//   out[row, col] += 2.0 * sum_r xa[row, g*16+r] * lora_B[m, c_full, r]
// where xa[row, g*16+r] = sum_d x[row,d] * lora_A[m, g*16+r, d],
//       m = row/2048, c_full = g*1024 + (col - g*2048).
// Strategy: bf16 MFMA for the big GEMM (threshold 0.1156 >> bf16 error),
// low-rank LoRA fused into the epilogue.
// ---------------------------------------------------------------------------

typedef __bf16 bf16;
typedef float f32x4 __attribute__((ext_vector_type(4)));
typedef bf16 bf16x8 __attribute__((ext_vector_type(8)));
typedef bf16 bf16x4 __attribute__((ext_vector_type(4)));

#define MT 16384   // total token rows (16*1024)
#define DIM 4096   // in features (K)
#define NOUT 4096  // out features

__device__ __forceinline__ void gld_lds16(const void* g, void* l) {
    // async global->LDS, 16B per lane; LDS dest = wave-uniform base + lane*16
    __builtin_amdgcn_global_load_lds(
        (const __attribute__((address_space(1))) unsigned int*)g,
        (__attribute__((address_space(3))) unsigned int*)l, 16, 0, 0);
}

// ---------------------------------------------------------------------------
// K0: convert weight [4096,4096] and lora_A [8,32,4096] fp32 -> bf16
// ---------------------------------------------------------------------------
__global__ __launch_bounds__(256) void cvt_w_a(const float* __restrict__ wsrc,
                                               const float* __restrict__ asrc,
                                               bf16* __restrict__ wdst,
                                               bf16* __restrict__ adst) {
    const size_t WN = (size_t)NOUT * DIM;  // 16777216
    size_t i = ((size_t)blockIdx.x * 256 + threadIdx.x) * 8;
    const float* s;
    bf16* d;
    size_t off;
    if (i < WN) { s = wsrc; d = wdst; off = i; }
    else        { s = asrc; d = adst; off = i - WN; }
    f32x4 v0 = *(const f32x4*)(s + off);
    f32x4 v1 = *(const f32x4*)(s + off + 4);
    bf16x8 o;
    o[0] = (bf16)v0.x; o[1] = (bf16)v0.y; o[2] = (bf16)v0.z; o[3] = (bf16)v0.w;
    o[4] = (bf16)v1.x; o[5] = (bf16)v1.y; o[6] = (bf16)v1.z; o[7] = (bf16)v1.w;
    *(bf16x8*)(d + off) = o;
}

// ---------------------------------------------------------------------------
// K1: per 32-token block: convert x fp32->bf16 (write to ws for K2), and
// compute xa[row, 0..31] = x_row . lora_A[m]^T via 16x16x32 bf16 MFMA.
// 4 waves: all stage; waves 0,1 each compute 16 tokens x 32 cols.
// ---------------------------------------------------------------------------
__global__ __launch_bounds__(256) void xa_cvt_kernel(const float* __restrict__ x,
                                                     const bf16* __restrict__ ab,
                                                     bf16* __restrict__ xb,
                                                     float* __restrict__ xa) {
    __shared__ __align__(16) bf16 xs[32 * 64];  // 4 KB
    __shared__ __align__(16) bf16 as[32 * 64];  // 4 KB
    const int tid = threadIdx.x;
    const int w = tid >> 6, lane = tid & 63;
    const int row0 = blockIdx.x * 32;
    const int m = row0 >> 11;  // adapter index (32 | 2048)

    f32x4 zz = {0.f, 0.f, 0.f, 0.f};
    f32x4 acc[2] = {zz, zz};

    // lora_A staging: wave w covers rows [w*8, w*8+8) of the 32x64 tile
    const char* aSrc = (const char*)ab +
        ((size_t)(m * 32 + w * 8 + (lane >> 3)) * DIM + (size_t)(lane & 7) * 8) * 2;
    bf16* asDst = &as[w * 512];

    for (int kt = 0; kt < DIM / 64; ++kt) {
        // stage x tile [32 tok][64 k]: fp32 load -> bf16 -> LDS + global ws
#pragma unroll
        for (int i = 0; i < 2; ++i) {
            int flat = i * 1024 + tid * 4;
            int r = flat >> 6;
            int k = flat & 63;
            const float* sp = x + (size_t)(row0 + r) * DIM + kt * 64 + k;
            f32x4 v = *(const f32x4*)sp;
            bf16x4 b;
            b[0] = (bf16)v.x; b[1] = (bf16)v.y; b[2] = (bf16)v.z; b[3] = (bf16)v.w;
            *(bf16x4*)(&xs[flat]) = b;
            *(bf16x4*)(xb + (size_t)(row0 + r) * DIM + kt * 64 + k) = b;
        }
        gld_lds16(aSrc + (size_t)kt * 128, asDst);
        __syncthreads();
        if (w < 2) {
#pragma unroll
            for (int kk = 0; kk < 2; ++kk) {
                int ko = kk * 32 + ((lane >> 4) << 3);
                bf16x8 av = *(const bf16x8*)(&xs[(w * 16 + (lane & 15)) * 64 + ko]);
#pragma unroll
                for (int n = 0; n < 2; ++n) {
                    bf16x8 bv = *(const bf16x8*)(&as[(n * 16 + (lane & 15)) * 64 + ko]);
                    acc[n] = __builtin_amdgcn_mfma_f32_16x16x32_bf16(av, bv, acc[n], 0, 0, 0);
                }
            }
        }
        __syncthreads();
    }
    if (w < 2) {
#pragma unroll
        for (int n = 0; n < 2; ++n) {
#pragma unroll
            for (int j = 0; j < 4; ++j) {
                int row = row0 + w * 16 + ((lane >> 4) << 2) + j;
                xa[(size_t)row * 32 + n * 16 + (lane & 15)] = acc[n][j];
            }
        }
    }
}

// ---------------------------------------------------------------------------
// K2: main GEMM (m97 structure): 128x128 tile, BK=32, 4 waves (2x2), each
// wave 4x4 fragments of 16x16x32 bf16. global_load_lds 16B staging, 2-barrier
// K-loop. Epilogue: bias + fused rank-16 LoRA correction.
// ---------------------------------------------------------------------------
__global__ __launch_bounds__(256) void gemm_lora_kernel(
    const bf16* __restrict__ xb, const bf16* __restrict__ wb,
    const float* __restrict__ bias, const float* __restrict__ xa,
    const float* __restrict__ loraB, float* __restrict__ out) {
    __shared__ __align__(16) bf16 As[128 * 32];  // 8 KB
    __shared__ __align__(16) bf16 Bs[128 * 32];  // 8 KB
    const int tid = threadIdx.x;
    const int w = tid >> 6, lane = tid & 63;

    // XCD-aware swizzle (grid = 4096, divisible by 8 -> bijective)
    const int bid = blockIdx.x;
    const int cpx = gridDim.x >> 3;
    const int swz = (bid & 7) * cpx + (bid >> 3);
    const int rt = swz & 127;  // 128 row tiles; consecutive swz share ct (B-panel L2 reuse)
    const int ct = swz >> 7;   // 32 col tiles
    const int row0 = rt * 128, col0 = ct * 128;
    const int wrow = (w >> 1) * 64, wcol = (w & 1) * 64;

    f32x4 zz = {0.f, 0.f, 0.f, 0.f};
    f32x4 acc[4][4];
#pragma unroll
    for (int mm = 0; mm < 4; ++mm)
#pragma unroll
        for (int nn = 0; nn < 4; ++nn) acc[mm][nn] = zz;

    // staging: 8 chunks of 1024B per matrix; wave w does chunks {2w, 2w+1}
    // chunk rows = chunk*16 + lane/4, k-byte = (lane&3)*16
    const char* aSrc0 = (const char*)xb +
        ((size_t)(row0 + w * 32 + (lane >> 2)) * DIM + (size_t)(lane & 3) * 8) * 2;
    const char* bSrc0 = (const char*)wb +
        ((size_t)(col0 + w * 32 + (lane >> 2)) * DIM + (size_t)(lane & 3) * 8) * 2;
    const size_t rstep = (size_t)16 * DIM * 2;  // 16 rows
    bf16* ldsA0 = &As[(w * 2 + 0) * 512];
    bf16* ldsA1 = &As[(w * 2 + 1) * 512];
    bf16* ldsB0 = &Bs[(w * 2 + 0) * 512];
    bf16* ldsB1 = &Bs[(w * 2 + 1) * 512];

    for (int kt = 0; kt < DIM / 32; ++kt) {
        const size_t kb = (size_t)kt * 64;  // 32 bf16 = 64 bytes per K step
        gld_lds16(aSrc0 + kb, ldsA0);
        gld_lds16(aSrc0 + rstep + kb, ldsA1);
        gld_lds16(bSrc0 + kb, ldsB0);
        gld_lds16(bSrc0 + rstep + kb, ldsB1);
        __syncthreads();
        const int ko = (lane >> 4) << 3;  // k element offset for this lane group
        bf16x8 af[4], bg[4];
#pragma unroll
        for (int mm = 0; mm < 4; ++mm)
            af[mm] = *(const bf16x8*)(&As[(wrow + mm * 16 + (lane & 15)) * 32 + ko]);
#pragma unroll
        for (int nn = 0; nn < 4; ++nn)
            bg[nn] = *(const bf16x8*)(&Bs[(wcol + nn * 16 + (lane & 15)) * 32 + ko]);
#pragma unroll
        for (int mm = 0; mm < 4; ++mm)
#pragma unroll
            for (int nn = 0; nn < 4; ++nn)
                acc[mm][nn] = __builtin_amdgcn_mfma_f32_16x16x32_bf16(af[mm], bg[nn],
                                                                      acc[mm][nn], 0, 0, 0);
        __syncthreads();
    }

    // Epilogue: C layout col = lane&15, row = (lane>>4)*4 + j
    const int madp = row0 >> 11;  // adapter (128 | 2048)
    int g;
    if (col0 < 1024) g = 0;
    else if (col0 >= 2048 && col0 < 3072) g = 1;
    else g = -1;

#pragma unroll
    for (int nn = 0; nn < 4; ++nn) {
        const int col = col0 + wcol + nn * 16 + (lane & 15);
        const float bz = bias[col];
        float bl[16];
        if (g >= 0) {
            const int cfull = (g << 10) + (col - (g << 11));
            const float* bp = loraB + ((size_t)madp * 2048 + cfull) * 16;
#pragma unroll
            for (int r4 = 0; r4 < 4; ++r4) {
                f32x4 t = *(const f32x4*)(bp + r4 * 4);
                bl[r4 * 4 + 0] = t.x; bl[r4 * 4 + 1] = t.y;
                bl[r4 * 4 + 2] = t.z; bl[r4 * 4 + 3] = t.w;
            }
        }
#pragma unroll
        for (int mm = 0; mm < 4; ++mm) {
#pragma unroll
            for (int j = 0; j < 4; ++j) {
                const int row = row0 + wrow + mm * 16 + ((lane >> 4) << 2) + j;
                float v = acc[mm][nn][j] + bz;
                if (g >= 0) {
                    const float* xp = xa + (size_t)row * 32 + (g << 4);
                    float dot = 0.f;
#pragma unroll
                    for (int r4 = 0; r4 < 4; ++r4) {
                        f32x4 t = *(const f32x4*)(xp + r4 * 4);
                        dot += t.x * bl[r4 * 4 + 0] + t.y * bl[r4 * 4 + 1] +
                               t.z * bl[r4 * 4 + 2] + t.w * bl[r4 * 4 + 3];
                    }
                    v += 2.0f * dot;
                }
                out[(size_t)row * NOUT + col] = v;
            }
        }
    }
}

// ---------------------------------------------------------------------------
extern "C" void kernel_launch(void* const* d_in, const int* in_sizes, int n_in,
                              void* d_out, int out_size, void* d_ws, size_t ws_size,
                              hipStream_t stream) {
    const float* x      = (const float*)d_in[0];  // [16,1024,4096]
    const float* weight = (const float*)d_in[1];  // [4096,4096]
    const float* bias   = (const float*)d_in[2];  // [4096]
    const float* lora_A = (const float*)d_in[3];  // [8,32,4096]
    const float* lora_B = (const float*)d_in[4];  // [8,2048,16]
    float* out = (float*)d_out;                   // [16384,4096]

    char* ws = (char*)d_ws;
    bf16* xb = (bf16*)ws;                                    // 128 MB
    bf16* wb = (bf16*)(ws + (size_t)134217728);              // 32 MB
    bf16* ab = (bf16*)(ws + (size_t)134217728 + 33554432);   // 2 MB
    float* xa = (float*)(ws + (size_t)134217728 + 33554432 + 2097152);  // 2 MB

    // K0: weight + lora_A -> bf16.  (16777216 + 1048576) / (256*8) = 8704 blocks
    cvt_w_a<<<8704, 256, 0, stream>>>(weight, lora_A, wb, ab);
    // K1: x -> bf16 + xa = x . A^T.  16384/32 = 512 blocks
    xa_cvt_kernel<<<512, 256, 0, stream>>>(x, ab, xb, xa);
    // K2: main GEMM + fused bias/LoRA epilogue. (16384/128)*(4096/128) = 4096 blocks
    gemm_lora_kernel<<<4096, 256, 0, stream>>>(xb, wb, bias, xa, lora_B, out);
}